// Round 6
// baseline (548.568 us; speedup 1.0000x reference)
//
#include <hip/hip_runtime.h>

typedef __bf16 bf16x8 __attribute__((ext_vector_type(8)));
typedef __bf16 bf16x4 __attribute__((ext_vector_type(4)));
typedef float  f32x4  __attribute__((ext_vector_type(4)));

// ---------- problem constants ----------
constexpr int DIL[9]   = {99,200,200,200,200,200,200,200,200};
constexpr int DOL[9]   = {200,200,200,101,200,200,200,200,1};
constexpr int KTL[9]   = {4,7,7,7,8,7,7,7,7};
constexpr int NTL[9]   = {13,13,13,8,13,13,13,13,1};   // L3 padded 7->8 frags
constexpr int NPADL[9] = {208,208,208,128,208,208,208,208,16};
constexpr long long PERML[9] = {26624,46592,46592,28672,53248,46592,46592,46592,3584};
constexpr long long WOFFL[9] = {0,638976,1757184,2875392,3563520,4841472,5959680,7077888,8196096};
constexpr int BOFFL[9] = {0,4992,9984,14976,18048,23040,28032,33024,38016};
constexpr int CUMTB[9] = {0,312,858,1404,1740,2364,2910,3456,4002}; // weight pack blocks
constexpr int SB0L[9]  = {0,0,1,0,1,1,0,1,0};   // WB parity holding slice 0 at layer entry

// workspace layout (bytes)
constexpr size_t WS_ANCH = 0;
constexpr size_t WS_BIAS = 512;
constexpr size_t WS_W    = 196608;

__device__ __forceinline__ unsigned short f2bf(float f) {
  union { float f; unsigned u; } v; v.f = f;
  unsigned r = v.u + 0x7fffu + ((v.u >> 16) & 1u);   // RTNE
  return (unsigned short)(r >> 16);
}

__device__ __forceinline__ float sp100(float x) {
  float e = __expf(-100.f * fabsf(x));
  return fmaxf(x, 0.f) + 0.01f * __logf(1.f + e);
}

// async global->LDS DMA, 16B/lane; LDS dest wave-uniform base (+lane*16 by HW)
__device__ __forceinline__ void gl_lds16(const void* g, void* l) {
  __builtin_amdgcn_global_load_lds(
      (const __attribute__((address_space(1))) void*)g,
      (__attribute__((address_space(3))) void*)l, 16, 0, 0);
}

// ---------- combined prep: weight/bias pack + pred zero + anchors MLP ----------
struct PrepArgs {
  const float* ew[9]; const float* eb[9];
  const float* lat; const float* ac;
  const float* pw0; const float* pb0;
  const float* pw1; const float* pb1;
  const float* pw2; const float* pb2;
};

__global__ void prep_k(PrepArgs a, unsigned short* __restrict__ wsW,
                       float* __restrict__ wsBias, float* __restrict__ wsAnch,
                       float* __restrict__ out) {
  const int bid = blockIdx.x, t = threadIdx.x;
  if (bid < 4044) {
    // weight pack -> fragment-major: [m][kt][nt][lane][8]
    int L = 0;
#pragma unroll
    for (int l = 1; l < 9; ++l) if (bid >= CUMTB[l]) L = l;
    const int NT = NTL[L], DI = DIL[L], DO = DOL[L];
    const int perm = KTL[L] * NT * 64;
    long tid = (long)(bid - CUMTB[L]) * 256 + t;
    int m = (int)(tid / perm);
    int q = (int)(tid - (long)m * perm);
    int f = q >> 6;
    int lane = q & 63;
    int kt = f / NT, nt = f - kt * NT;
    int o  = nt * 16 + (lane & 15);
    int k0 = kt * 32 + (lane >> 4) * 8;
    float sc = (L == 4) ? 0.70710678118654752f : 1.0f;
    const float* wrow = a.ew[L] + ((long)m * DO + o) * DI;
    unsigned short ov[8];
#pragma unroll
    for (int j = 0; j < 8; ++j) {
      int k = k0 + j, ks;
      if (L == 4) ks = (k < 128) ? (k < 101 ? k : -1) : (k < 227 ? k - 27 : -1);
      else        ks = (k < DI) ? k : -1;
      float v = (o < DO && ks >= 0) ? wrow[ks] * sc : 0.f;
      ov[j] = f2bf(v);
    }
    *(uint4*)(wsW + WOFFL[L] + (long)m * PERML[L] + ((long)f * 64 + lane) * 8) = *(uint4*)ov;
  } else if (bid < 4194) {
    int b = (bid - 4044) * 256 + t;
    if (b < 38400) {
      int L = 0;
#pragma unroll
      for (int l = 1; l < 9; ++l) if (b >= BOFFL[l]) L = l;
      int NP = NPADL[L], DO = DOL[L];
      int r = b - BOFFL[L];
      int m = r / NP, o = r - m * NP;
      if (b < 38016 + 384) wsBias[b] = (m < 24 && o < DO) ? a.eb[L][m * DO + o] : 0.f;
    }
  } else if (bid < 4210) {
    out[(bid - 4194) * 256 + t] = 0.f;             // pred zero-init
  } else {
    __shared__ float g[64], h1[256], h2[256];
    if (t < 64) g[t] = a.lat[t];
    __syncthreads();
    { float s = a.pb0[t]; for (int i = 0; i < 64;  ++i) s += g[i]  * a.pw0[i*256 + t]; h1[t] = fmaxf(s, 0.f); }
    __syncthreads();
    { float s = a.pb1[t]; for (int i = 0; i < 256; ++i) s += h1[i] * a.pw1[i*256 + t]; h2[t] = fmaxf(s, 0.f); }
    __syncthreads();
    if (t < 117) {
      float s = a.pb2[t];
      for (int i = 0; i < 256; ++i) s += h2[i] * a.pw2[i*117 + t];
      s += a.ac[t];
      wsAnch[t] = s; out[4096 + t] = s;
    } else if (t < 120) {
      wsAnch[t] = 0.f;
    }
  }
}

// ---------- fused ensemble MLP ----------
// Activation LDS: uint2 slot (g,p) = channels [4g..4g+3] of point p,
// idx = g*64 + (p ^ (g & 14))  -- mask 14 so groups (2j,2j+1) share one xor const.
__device__ __forceinline__ int xsw(int g, int p) { return g * 64 + (p ^ (g & 14)); }

template<int L, int NTG>
__device__ __forceinline__ void runLayer(int lane, int l15, int hi2, int wid, int m, int ntb,
    uint2* __restrict__ X, const uint2* __restrict__ X0, uint4* __restrict__ WB,
    const unsigned short* __restrict__ Wp, const float* __restrict__ Bp,
    float* __restrict__ sdfS)
{
  constexpr int KT = KTL[L], NT = NTL[L], SB0 = SB0L[L];
  constexpr int LNx = (L < 8) ? L + 1 : 8;
  const char* gsrc = (const char*)(Wp + WOFFL[L]   + (long)m * PERML[L])   + lane * 16;
  const char* gnxt = (const char*)(Wp + WOFFL[LNx] + (long)m * PERML[LNx]) + lane * 16;
  char* ldsWB = (char*)WB;                       // uniform DMA dest base
  const uint4* __restrict__ wbl = WB + lane + ntb * 64;   // B-read base
  const char* ldsX  = (const char*)X;
  const char* ldsX0 = (const char*)X0;
  const int pl  = hi2 * 1024 + l15 * 8;          // per-lane A base (byte, within tile)
  const int xce = hi2 * 16;                      // xor const, even ktt
  const int xco = xce | 64;                      // xor const, odd ktt

  f32x4 acc[4][NTG];
#pragma unroll
  for (int mf = 0; mf < 4; ++mf)
#pragma unroll
    for (int nt = 0; nt < NTG; ++nt) acc[mf][nt] = f32x4{0.f, 0.f, 0.f, 0.f};

#define ASTEP(k)                                                                     \
  if constexpr ((k) < KT) {                                                          \
    constexpr int sb = (SB0 + (k)) & 1;                                              \
    if constexpr ((k) + 1 < KT) {                                                    \
      _Pragma("unroll")                                                              \
      for (int j = 0; j < 4; ++j) {                                                  \
        int f = wid + 4 * j;                                                         \
        if (f < NT) gl_lds16(gsrc + (long)(((k) + 1) * NT + f) * 1024,               \
                             ldsWB + (sb ^ 1) * 13312 + f * 1024);                   \
      }                                                                              \
    } else if constexpr (L < 8) {                                                    \
      _Pragma("unroll")                                                              \
      for (int j = 0; j < 4; ++j) {                                                  \
        int f = wid + 4 * j;                                                         \
        if (f < NTL[LNx]) gl_lds16(gnxt + (long)f * 1024,                            \
                                   ldsWB + (sb ^ 1) * 13312 + f * 1024);             \
      }                                                                              \
    }                                                                                \
    constexpr int  ktt  = (L == 4 && (k) >= 4) ? (k) - 4 : (k);                      \
    constexpr bool uX0  = (L == 0) || (L == 4 && (k) >= 4);                          \
    const char* sA = uX0 ? ldsX0 : ldsX;                                             \
    const int ax = pl ^ ((ktt & 1) ? xco : xce);                                     \
    bf16x8 afr[4];                                                                   \
    _Pragma("unroll")                                                                \
    for (int mf = 0; mf < 4; ++mf) {                                                 \
      uint2 q0 = *(const uint2*)(sA + ktt * 4096 + mf * 128 + ax);                   \
      uint2 q1 = *(const uint2*)(sA + ktt * 4096 + mf * 128 + 512 + ax);             \
      uint4 q = make_uint4(q0.x, q0.y, q1.x, q1.y);                                  \
      afr[mf] = *(bf16x8*)&q;                                                        \
    }                                                                                \
    bf16x8 bfr[NTG];                                                                 \
    _Pragma("unroll")                                                                \
    for (int nt = 0; nt < NTG; ++nt) {                                               \
      uint4 qq = wbl[sb * 832 + nt * 64];                                            \
      bfr[nt] = *(bf16x8*)&qq;                                                       \
    }                                                                                \
    _Pragma("unroll")                                                                \
    for (int nt = 0; nt < NTG; ++nt)                                                 \
      _Pragma("unroll")                                                              \
      for (int mf = 0; mf < 4; ++mf)                                                 \
        acc[mf][nt] = __builtin_amdgcn_mfma_f32_16x16x32_bf16(bfr[nt], afr[mf],      \
                                                              acc[mf][nt], 0, 0, 0); \
    __syncthreads();                                                                 \
  }
  ASTEP(0) ASTEP(1) ASTEP(2) ASTEP(3) ASTEP(4) ASTEP(5) ASTEP(6) ASTEP(7)
#undef ASTEP

  // epilogue: bias + softplus100 + bf16 pack + LDS write
  const float* __restrict__ Bm = Bp + BOFFL[L] + m * NPADL[L];
  if constexpr (L < 8) {
    uint2 pk[4][NTG];
#pragma unroll
    for (int nt = 0; nt < NTG; ++nt) {
      int c0 = (ntb + nt) * 16 + hi2 * 4;
      float4 bb = *(const float4*)(Bm + c0);
#pragma unroll
      for (int mf = 0; mf < 4; ++mf) {
        float v0 = sp100(acc[mf][nt][0] + bb.x);
        float v1 = sp100(acc[mf][nt][1] + bb.y);
        float v2 = sp100(acc[mf][nt][2] + bb.z);
        float v3 = sp100(acc[mf][nt][3] + bb.w);
        bf16x4 w; w[0] = (__bf16)v0; w[1] = (__bf16)v1; w[2] = (__bf16)v2; w[3] = (__bf16)v3;
        pk[mf][nt] = *(uint2*)&w;
      }
    }
#pragma unroll
    for (int nt = 0; nt < NTG; ++nt) {
      int g = (ntb + nt) * 4 + hi2;
#pragma unroll
      for (int mf = 0; mf < 4; ++mf)
        X[xsw(g, mf * 16 + l15)] = pk[mf][nt];
    }
  } else {
    float b0 = Bm[0];
    if (hi2 == 0) {
#pragma unroll
      for (int mf = 0; mf < 4; ++mf) sdfS[mf * 16 + l15] = acc[mf][0][0] + b0;
    }
  }
  __syncthreads();
}

template<int NTG13>
__device__ __forceinline__ void runAll(int lane, int l15, int hi2, int wid, int m,
    int ntb13, int ntb8,
    uint2* __restrict__ X, const uint2* __restrict__ X0, uint4* __restrict__ WB,
    const unsigned short* __restrict__ Wp, const float* __restrict__ Bp,
    float* __restrict__ sdfS)
{
  runLayer<0, NTG13>(lane, l15, hi2, wid, m, ntb13, X, X0, WB, Wp, Bp, sdfS);
  runLayer<1, NTG13>(lane, l15, hi2, wid, m, ntb13, X, X0, WB, Wp, Bp, sdfS);
  runLayer<2, NTG13>(lane, l15, hi2, wid, m, ntb13, X, X0, WB, Wp, Bp, sdfS);
  runLayer<3, 2>    (lane, l15, hi2, wid, m, ntb8,  X, X0, WB, Wp, Bp, sdfS);
  runLayer<4, NTG13>(lane, l15, hi2, wid, m, ntb13, X, X0, WB, Wp, Bp, sdfS);
  runLayer<5, NTG13>(lane, l15, hi2, wid, m, ntb13, X, X0, WB, Wp, Bp, sdfS);
  runLayer<6, NTG13>(lane, l15, hi2, wid, m, ntb13, X, X0, WB, Wp, Bp, sdfS);
  runLayer<7, NTG13>(lane, l15, hi2, wid, m, ntb13, X, X0, WB, Wp, Bp, sdfS);
  runLayer<8, 1>    (lane, l15, hi2, wid, m, 0,     X, X0, WB, Wp, Bp, sdfS);
}

__global__ __launch_bounds__(256, 2) void mlp_k(
    const float* __restrict__ xyz, const float* __restrict__ lat,
    const float* __restrict__ anch, const unsigned short* __restrict__ Wp,
    const float* __restrict__ Bp, float* __restrict__ pred)
{
  __shared__ uint2 X[56 * 64];        // 224 ch x 64 pts (28.7 KB)
  __shared__ uint2 X0[32 * 64];       // 128 ch x 64 pts inp_net (16.4 KB)
  __shared__ uint4 WB[2 * 13 * 64];   // weight slices, 2 x 13 KB
  __shared__ float anchS[120];
  __shared__ float sdfS[64];

  const int t = threadIdx.x;
  const int lane = t & 63, wid = t >> 6;
  const int l15 = lane & 15, hi2 = lane >> 4;
  const int e  = blockIdx.x % 40;          // member<->XCD affinity (40 % 8 == 0)
  const int pt = blockIdx.x / 40;
  const int n0 = pt * 64;
  const int m  = (e < 32) ? (e >> 1) : (e - 16);
  const float mir = (e < 32 && (e & 1)) ? -1.f : 1.f;

  // issue layer-0 slice-0 DMA immediately (drained at first barrier)
  {
    const char* g0 = (const char*)(Wp + WOFFL[0] + (long)m * PERML[0]) + lane * 16;
#pragma unroll
    for (int j = 0; j < 4; ++j) {
      int f = wid + 4 * j;
      if (f < 13) gl_lds16(g0 + (long)f * 1024, (char*)WB + f * 1024);
    }
  }

  // zero pad groups (feed MFMA against zero weights; must be finite)
  for (int i = 52 * 64 + t; i < 56 * 64; i += 256) X[i]  = make_uint2(0u, 0u);
  for (int i = 24 * 64 + t; i < 32 * 64; i += 256) X0[i] = make_uint2(0u, 0u);
  if (t < 120) anchS[t] = anch[t];
  __syncthreads();

  // stage inp_net (99 ch) for 64 points into X0
  const float ax = anchS[e * 3], ay = anchS[e * 3 + 1], az = anchS[e * 3 + 2];
  for (int it = 0; it < 32; ++it) {
    int row = it * 2 + (t >> 7);
    int c = t & 127;
    long n = n0 + row;
    if (c < 99) {
      float v;
      if (c >= 67)      v = lat[n * 1344 + 64 + e * 32 + (c - 67)];
      else if (c >= 3)  v = lat[n * 1344 + (c - 3)];
      else {
        v = xyz[n * 3 + c] - ((c == 0) ? ax : (c == 1) ? ay : az);
        if (c == 0) v *= mir;
      }
      int g = c >> 2;
      ((unsigned short*)&X0[xsw(g, row)])[c & 3] = f2bf(v);
    }
  }
  __syncthreads();

  const int ng = wid;   // 4 N-groups, each wave covers all 64 points
  if (ng == 0) runAll<4>(lane, l15, hi2, wid, m, 0,                0,       X, X0, WB, Wp, Bp, sdfS);
  else         runAll<3>(lane, l15, hi2, wid, m, 4 + (ng - 1) * 3, 2 * ng,  X, X0, WB, Wp, Bp, sdfS);

  // distance softmax over 40 anchors + atomic blend
  if (t < 64) {
    long n = n0 + t;
    float px = xyz[n * 3], py = xyz[n * 3 + 1], pz = xyz[n * 3 + 2];
    float den = 1e-6f + __expf(-20.f);
    for (int j = 0; j < 39; ++j) {
      float dx = anchS[j * 3] - px, dy = anchS[j * 3 + 1] - py, dz = anchS[j * 3 + 2] - pz;
      float d = sqrtf(dx * dx + dy * dy + dz * dz) + 1e-5f;
      den += __expf(-100.f * d * d);
    }
    float num;
    if (e == 39) num = __expf(-20.f);
    else {
      float dx = anchS[e * 3] - px, dy = anchS[e * 3 + 1] - py, dz = anchS[e * 3 + 2] - pz;
      float d = sqrtf(dx * dx + dy * dy + dz * dz) + 1e-5f;
      num = __expf(-100.f * d * d);
    }
    atomicAdd(&pred[n], (num / den) * sdfS[t]);
  }
}

extern "C" void kernel_launch(void* const* d_in, const int* in_sizes, int n_in,
                              void* d_out, int out_size, void* d_ws, size_t ws_size,
                              hipStream_t stream) {
  PrepArgs a;
  const float* xyz = (const float*)d_in[0];
  a.lat = (const float*)d_in[1];
  a.ac  = (const float*)d_in[2];
  a.pw0 = (const float*)d_in[3]; a.pb0 = (const float*)d_in[4];
  a.pw1 = (const float*)d_in[5]; a.pb1 = (const float*)d_in[6];
  a.pw2 = (const float*)d_in[7]; a.pb2 = (const float*)d_in[8];
  for (int l = 0; l < 9; ++l) { a.ew[l] = (const float*)d_in[9 + 2*l]; a.eb[l] = (const float*)d_in[10 + 2*l]; }

  float* out = (float*)d_out;                 // [0,4096) pred, [4096,4213) anch
  char* ws = (char*)d_ws;
  float* wsAnch = (float*)(ws + WS_ANCH);
  float* wsBias = (float*)(ws + WS_BIAS);
  unsigned short* wsW = (unsigned short*)(ws + WS_W);

  prep_k<<<4211, 256, 0, stream>>>(a, wsW, wsBias, wsAnch, out);
  mlp_k<<<2560, 256, 0, stream>>>(xyz, a.lat, wsAnch, wsW, wsBias, out);
}